// Round 9
// baseline (48.020 us; speedup 1.0000x reference)
//
#include <hip/hip_runtime.h>

// Diagonal depthwise conv, derived from the reference:
//   View x as X[R][W], R = B*C*H = 131072, W = 256.
//   out[r][w] = bias[c] + sum_k weight[c][k] * X[(r+2-k) mod R][w+k-2]
//   where c = (r / H) % C, column OOB -> 0, row index wraps mod R
//   (torch.roll on the fully-flattened tensor wraps across h/c/b).
//
// Round-8 (= round-7 structure + clamp-remap fix):
//  * 8 rows x 4 cols per thread; w0 = lane*4 -> dense 1KB/wave nt stores;
//    nt keeps write stream out of L2/L3 so x stays L3-resident.
//  * Per source row, window F[0..7] = x[base-2 .. base+5] via TWO 16B loads
//    at base-2 / base+2 (8B-aligned type, gfx950 handles unaligned dwordx4).
//  * ROUND-7 BUG FIX: when the first load clamps (rk==0 && w0==0) A holds
//    cols 0..3, so F[2],F[3] must come from A.x,A.y (not A.z,A.w); when the
//    last load clamps (rk==RTOT-1 && w0==252) B holds cols 252..255, so
//    F[4],F[5] must come from B.z,B.w. Edge-masking zeroes F[0,1]/F[6,7].

#define WIDTH 256
#define RTOT  131072            // 8 * 64 * 256
#define NTOT  (RTOT * WIDTH)    // 33,554,432 (fits int)
#define NCH   64
#define KS    5
#define ROWS  8                 // output rows per thread

typedef float f32x4 __attribute__((ext_vector_type(4)));
typedef f32x4 f32x4_a8 __attribute__((aligned(8)));   // 8B-aligned 16B load

__global__ __launch_bounds__(256) void diag_dwconv_kernel(
    const float* __restrict__ x,
    const float* __restrict__ wgt,    // [C][1][KS] flat
    const float* __restrict__ bias,   // [C]
    float* __restrict__ out)
{
    int v  = blockIdx.x * blockDim.x + threadIdx.x;  // [0, RTOT/ROWS * 64)
    int rq = (v >> 6) << 3;          // base output row (wave-uniform, 8-aligned)
    int w0 = (v & 63) << 2;          // 4-col segment; lanes cover one full row
    int c  = __builtin_amdgcn_readfirstlane((rq >> 8) & (NCH - 1));

    float wv[KS];
    #pragma unroll
    for (int k = 0; k < KS; ++k) wv[k] = wgt[c * KS + k];   // scalar loads
    float b = bias[c];

    float acc[ROWS][4];
    #pragma unroll
    for (int i = 0; i < ROWS; ++i)
        #pragma unroll
        for (int jj = 0; jj < 4; ++jj) acc[i][jj] = b;

    bool edgeL = (w0 == 0);           // lane 0 of the wave
    bool edgeR = (w0 == WIDTH - 4);   // lane 63 of the wave

    #pragma unroll
    for (int j = -2; j <= ROWS + 1; ++j) {    // source row rq + j (12 rows)
        int rk = rq + j;
        if (rk < 0)          rk += RTOT;      // wrap across flat tensor
        else if (rk >= RTOT) rk -= RTOT;
        int base = rk * WIDTH + w0;

        int aoff = base - 2;
        bool clampA = (aoff < 0);             // only rk==0 && w0==0
        if (clampA) aoff = 0;
        int boff = base + 2;
        bool clampB = (boff > NTOT - 4);      // only rk==RTOT-1 && w0==252
        if (clampB) boff = NTOT - 4;

        f32x4 A = *reinterpret_cast<const f32x4_a8*>(x + aoff);  // w0-2 .. w0+1
        f32x4 B = *reinterpret_cast<const f32x4_a8*>(x + boff);  // w0+2 .. w0+5

        float F[8] = { A.x, A.y, A.z, A.w, B.x, B.y, B.z, B.w };
        // clamp remap: clamped A holds cols 0..3 -> F[2]=col0, F[3]=col1;
        //              clamped B holds cols 252..255 -> F[4]=col254, F[5]=col255
        if (clampA) { F[2] = A.x; F[3] = A.y; }
        if (clampB) { F[4] = B.z; F[5] = B.w; }
        if (edgeL)  { F[0] = 0.f; F[1] = 0.f; }  // cols < 0 contribute 0
        if (edgeR)  { F[6] = 0.f; F[7] = 0.f; }  // cols >= WIDTH contribute 0

        #pragma unroll
        for (int i = 0; i < ROWS; ++i) {      // output row rq + i
            int k = i - j + 2;                // tap index (compile-time const)
            if (k >= 0 && k < KS) {
                #pragma unroll
                for (int jj = 0; jj < 4; ++jj)
                    acc[i][jj] = fmaf(wv[k], F[jj + k], acc[i][jj]);
            }
        }
    }

    #pragma unroll
    for (int i = 0; i < ROWS; ++i) {
        int ob = (rq + i) * WIDTH + w0;
        f32x4 o = { acc[i][0], acc[i][1], acc[i][2], acc[i][3] };
        __builtin_nontemporal_store(o, reinterpret_cast<f32x4*>(out + ob));
    }
}

extern "C" void kernel_launch(void* const* d_in, const int* in_sizes, int n_in,
                              void* d_out, int out_size, void* d_ws, size_t ws_size,
                              hipStream_t stream) {
    const float* x    = (const float*)d_in[0];
    const float* wgt  = (const float*)d_in[1];
    const float* bias = (const float*)d_in[2];
    float* out        = (float*)d_out;

    // one thread per 32 outputs (8 rows x 4 cols): 33,554,432 / 32 = 1,048,576
    int threads = 256;
    int blocks  = (out_size / 32 + threads - 1) / threads;   // 4096
    diag_dwconv_kernel<<<blocks, threads, 0, stream>>>(x, wgt, bias, out);
}